// Round 17
// baseline (51.836 us; speedup 1.0000x reference)
//
#include <hip/hip_runtime.h>
#include <hip/hip_bf16.h>
#include <cstdint>

// PiNet: B=8192, I=12, O=512, DEG=4.
// R16: R15 base (BB=32 full-O gemm, fp16-staged fold, constexpr tables) with
// the gemm K-loop restructured: 4 Ash buffers -> 2 kts per barrier window
// (14 barriers instead of 28), and hot-loop barriers are raw s_barrier +
// lgkmcnt(0) only (B prefetches stay in flight across barriers).

#define NB 8192
#define NI 12
#define NO 512
#define T_TOTAL 1820
#define TPAD 1856          // 29 * 64
#define NKT 29
#define B2 13
#define B3 91
#define B4 455

typedef __attribute__((ext_vector_type(8))) _Float16 f16x8;
typedef __attribute__((ext_vector_type(4))) float f32x4;

#define MFMA16(a, b, c) __builtin_amdgcn_mfma_f32_16x16x32_f16(a, b, c, 0, 0, 0)

__device__ __forceinline__ unsigned short f2h(float f) {
    _Float16 h = (_Float16)f;
    return __builtin_bit_cast(unsigned short, h);
}
__device__ __forceinline__ float h2f(unsigned short u) {
    return (float)__builtin_bit_cast(_Float16, u);
}

// ---------- compile-time tables ----------
constexpr int H2c(int n) { return n * (n + 1) / 2; }
constexpr int H3c(int n) { return n * (n + 1) * (n + 2) / 6; }
constexpr int rank2c(int a, int b) {
    int r = 0;
    for (int j = 0; j < a; ++j) r += NI - j;
    return r + (b - a);
}

struct alignas(16) MPArr { uint32_t v[TPAD]; };
constexpr MPArr gen_mp() {
    MPArr m{};
    for (int t = 0; t < TPAD; ++t) {
        uint32_t v = 0;
        if (t == 0) {
            v = 0;
        } else if (t < B2) {
            v = (uint32_t)t;
        } else if (t < B3) {
            int r = t - B2, a = 0;
            while (r >= NI - a) { r -= NI - a; ++a; }
            int b = a + r;
            v = (uint32_t)(1 + a) | ((uint32_t)(1 + b) << 16);
        } else if (t < B4) {
            int r = t - B3, a = 0;
            while (r >= H2c(NI - a)) { r -= H2c(NI - a); ++a; }
            int b = a;
            while (r >= NI - b) { r -= NI - b; ++b; }
            int c = b + r;
            v = (uint32_t)(13 + rank2c(a, b)) | ((uint32_t)(1 + c) << 16);
        } else if (t < T_TOTAL) {
            int r = t - B4, a = 0;
            while (r >= H3c(NI - a)) { r -= H3c(NI - a); ++a; }
            int b = a;
            while (r >= H2c(NI - b)) { r -= H2c(NI - b); ++b; }
            int c = b;
            while (r >= NI - c) { r -= NI - c; ++c; }
            int d = c + r;
            v = (uint32_t)(13 + rank2c(a, b)) | ((uint32_t)(13 + rank2c(c, d)) << 16);
        }
        m.v[t] = v;          // t in [1820,1856): monomial = 1, weight 0
    }
    return m;
}
__device__ constexpr MPArr MP = gen_mp();

struct FoldArr {
    uint16_t tup2[78];  float rk2[78];
    uint16_t tup3[364]; float rk3[364];
    uint16_t tup4[1368]; float rk4[1368];
};
constexpr FoldArr gen_fold() {
    FoldArr f{};
    for (int q = 0; q < 78; ++q) {
        int r = q, a = 0;
        while (r >= NI - a) { r -= NI - a; ++a; }
        int b = a + r;
        f.tup2[q] = (uint16_t)(a | (b << 4));
        f.rk2[q] = (a == b) ? 0.5f : 1.0f;
    }
    for (int q = 0; q < 364; ++q) {
        int r = q, a = 0;
        while (r >= H2c(NI - a)) { r -= H2c(NI - a); ++a; }
        int b = a;
        while (r >= NI - b) { r -= NI - b; ++b; }
        int c = b + r;
        f.tup3[q] = (uint16_t)(a | (b << 4) | (c << 8));
        int k = 1, run = 1;
        if (b == a) { ++run; k *= run; } else run = 1;
        if (c == b) { ++run; k *= run; } else run = 1;
        f.rk3[q] = 1.0f / (float)k;
    }
    for (int q = 0; q < 1365; ++q) {
        int r = q, a = 0;
        while (r >= H3c(NI - a)) { r -= H3c(NI - a); ++a; }
        int b = a;
        while (r >= H2c(NI - b)) { r -= H2c(NI - b); ++b; }
        int c = b;
        while (r >= NI - c) { r -= NI - c; ++c; }
        int d = c + r;
        f.tup4[q] = (uint16_t)(a | (b << 4) | (c << 8) | (d << 12));
        int k = 1, run = 1;
        if (b == a) { ++run; k *= run; } else run = 1;
        if (c == b) { ++run; k *= run; } else run = 1;
        if (d == c) { ++run; k *= run; } else run = 1;
        f.rk4[q] = 1.0f / (float)k;
    }
    return f;
}
__device__ constexpr FoldArr FT = gen_fold();

// ---------- fold: fp16 LDS staging (2 blocks/CU) + per-t orbit gather ----------
__global__ __launch_bounds__(1024, 8) void pinet_fold(
    const float* __restrict__ w0, const float* __restrict__ w1,
    const float* __restrict__ w2, const float* __restrict__ w3,
    const float* __restrict__ w4, ushort* __restrict__ Wh) {
    __shared__ ushort sw4h[20736];
    __shared__ ushort sw3h[1728];
    __shared__ ushort sw2h[144];
    const int tid = threadIdx.x;
    const int o = blockIdx.x;

    {   // coalesced staging, f32 -> fp16
        const float4* g4 = (const float4*)(w4 + o * 20736);
        for (int i = tid; i < 5184; i += 1024) {
            float4 v = g4[i];
            ushort4 h = {f2h(v.x), f2h(v.y), f2h(v.z), f2h(v.w)};
            *(ushort4*)&sw4h[i * 4] = h;
        }
        if (tid < 432) {
            float4 v = ((const float4*)(w3 + o * 1728))[tid];
            ushort4 h = {f2h(v.x), f2h(v.y), f2h(v.z), f2h(v.w)};
            *(ushort4*)&sw3h[tid * 4] = h;
        }
        if (tid < 36) {
            float4 v = ((const float4*)(w2 + o * 144))[tid];
            ushort4 h = {f2h(v.x), f2h(v.y), f2h(v.z), f2h(v.w)};
            *(ushort4*)&sw2h[tid * 4] = h;
        }
    }
    __syncthreads();

#define W4P(p, q, r, s_) h2f(sw4h[(p) * 1728 + (q) * 144 + (r) * 12 + (s_)])
#define W3P(p, q, r)     h2f(sw3h[(p) * 144 + (q) * 12 + (r)])
    for (int t = tid; t < TPAD; t += 1024) {
        float s = 0.0f;
        if (t == 0) {
            s = w0[o];
        } else if (t < B2) {
            s = w1[o * 12 + (t - 1)];
        } else if (t < B3) {
            int q = t - B2; int tp = FT.tup2[q];
            int a = tp & 15, b = (tp >> 4) & 15;
            s = (h2f(sw2h[a * 12 + b]) + h2f(sw2h[b * 12 + a])) * FT.rk2[q];
        } else if (t < B4) {
            int q = t - B3; int tp = FT.tup3[q];
            int a = tp & 15, b = (tp >> 4) & 15, c = (tp >> 8) & 15;
            s = (W3P(a, b, c) + W3P(a, c, b) + W3P(b, a, c) +
                 W3P(b, c, a) + W3P(c, a, b) + W3P(c, b, a)) * FT.rk3[q];
        } else if (t < T_TOTAL) {
            int q = t - B4; int tp = FT.tup4[q];
            int a = tp & 15, b = (tp >> 4) & 15, c = (tp >> 8) & 15, d = (tp >> 12) & 15;
            float s4v =
                W4P(a,b,c,d) + W4P(a,b,d,c) + W4P(a,c,b,d) + W4P(a,c,d,b) +
                W4P(a,d,b,c) + W4P(a,d,c,b) + W4P(b,a,c,d) + W4P(b,a,d,c) +
                W4P(b,c,a,d) + W4P(b,c,d,a) + W4P(b,d,a,c) + W4P(b,d,c,a) +
                W4P(c,a,b,d) + W4P(c,a,d,b) + W4P(c,b,a,d) + W4P(c,b,d,a) +
                W4P(c,d,a,b) + W4P(c,d,b,a) + W4P(d,a,b,c) + W4P(d,a,c,b) +
                W4P(d,b,a,c) + W4P(d,b,c,a) + W4P(d,c,a,b) + W4P(d,c,b,a);
            s = s4v * FT.rk4[q];
        }
        Wh[((t >> 3) * NO + o) * 8 + (t & 7)] = f2h(s);
    }
#undef W4P
#undef W3P
}

// ---------- MFMA GEMM: out[b,o] = sum_t M[t][b] * Wt[t][o], fp16 ----------
// Block: 32 b x 512 o, 1024 threads (16 waves of 32b x 32o), grid 256 = 1/CU.
// 4 Ash buffers, 2 kts per barrier window, raw s_barrier + lgkmcnt(0) only.
__global__ __launch_bounds__(1024, 4) void pinet_gemm(
    const float* __restrict__ x, const ushort* __restrict__ Wh,
    float* __restrict__ out) {
    __shared__ float msm[32][93];           // per-b: {1, x0..x11, 78 deg2}
    __shared__ ushort Ash[4][32][8][8];     // [buf][b][t-octet slot (swz)][8 fp16]

    const int tid = threadIdx.x;
    const int b0 = blockIdx.x * 32;

    for (int idx = tid; idx < 32 * 13; idx += 1024) {
        int b = idx / 13, j = idx % 13;
        msm[b][j] = (j == 0) ? 1.0f : x[(b0 + b) * 12 + (j - 1)];
    }
    __syncthreads();
    for (int idx = tid; idx < 32 * 78; idx += 1024) {
        int b = idx / 78, q = idx % 78;
        uint32_t m2 = MP.v[B2 + q];
        msm[b][13 + q] = msm[b][m2 & 0xFFFFu] * msm[b][m2 >> 16];
    }

    const int l = tid & 63, wv = tid >> 6;  // 16 waves, wO = wv (512 o total)
    const int lm = l & 15, lg = l >> 4;
    const int o_w = wv * 32;
    const int bgen = tid & 31;
    const int task = tid >> 5;              // 0..31, 2 t's each
    const int sA = (task >> 2) ^ (bgen & 7);
    const int hOf = (task & 3) * 2;

    f32x4 acc[2][2] = {};
    f16x8 B0[2][2], B1[2][2];               // [os][chunk]

    auto gen = [&](int kt, int buf) {
        int t0 = kt * 64 + task * 2;
        uint2 mq = *(const uint2*)&MP.v[t0];
        const float* row = msm[bgen];
        float p0 = row[mq.x & 0xFFFFu] * row[mq.x >> 16];
        float p1 = row[mq.y & 0xFFFFu] * row[mq.y >> 16];
        ushort2 v = {f2h(p0), f2h(p1)};
        *(ushort2*)&Ash[buf][bgen][sA][hOf] = v;
    };
    auto loadB = [&](int kt, f16x8 (&B)[2][2]) {
#pragma unroll
        for (int os = 0; os < 2; ++os)
#pragma unroll
            for (int c = 0; c < 2; ++c) {
                int pk = kt * 8 + c * 4 + lg;
                B[os][c] = *(const f16x8*)(Wh + (pk * NO + o_w + os * 16 + lm) * 8);
            }
    };
    auto mfmaR = [&](int cur, f16x8 (&B)[2][2]) {
#pragma unroll
        for (int c = 0; c < 2; ++c) {
            f16x8 a[2];
#pragma unroll
            for (int bs = 0; bs < 2; ++bs) {
                int br = bs * 16 + lm;
                a[bs] = *(const f16x8*)&Ash[cur][br][(c * 4 + lg) ^ (br & 7)][0];
            }
#pragma unroll
            for (int bs = 0; bs < 2; ++bs)
#pragma unroll
                for (int os = 0; os < 2; ++os)
                    acc[bs][os] = MFMA16(a[bs], B[os][c], acc[bs][os]);
        }
    };

    __syncthreads();          // msm ready
    gen(0, 0);
    gen(1, 1);
    loadB(0, B0);
    loadB(1, B1);
    __syncthreads();          // Ash[0],Ash[1] ready

    // 13 windows x 2 kts: kts 0..25 computed, 26..28 handled in tail.
    for (int p = 0; p < 13; ++p) {
        const int k0 = 2 * p;
        gen(k0 + 2, (k0 + 2) & 3);          // writes bufs {2,3} or {0,1}
        gen(k0 + 3, (k0 + 3) & 3);
        mfmaR(k0 & 3, B0);                  // reads bufs {0,1} or {2,3}
        loadB(k0 + 2, B0);                  // global; stays in flight
        mfmaR((k0 + 1) & 3, B1);
        loadB(k0 + 3, B1);
        asm volatile("s_waitcnt lgkmcnt(0)" ::: "memory");
        __builtin_amdgcn_s_barrier();
        __builtin_amdgcn_sched_barrier(0);
    }
    // state: bufs 2,3 hold kts 26,27; B0=Wh(26), B1=Wh(27)
    gen(28, 0);                              // buf0 reads (kt 24) done pre-barrier
    mfmaR(2, B0);
    loadB(28, B0);
    mfmaR(3, B1);
    asm volatile("s_waitcnt lgkmcnt(0)" ::: "memory");
    __builtin_amdgcn_s_barrier();
    __builtin_amdgcn_sched_barrier(0);
    mfmaR(0, B0);                            // kt = 28

#pragma unroll
    for (int bs = 0; bs < 2; ++bs)
#pragma unroll
        for (int os = 0; os < 2; ++os) {
            int ob = o_w + os * 16 + lm;
#pragma unroll
            for (int r = 0; r < 4; ++r) {
                int bb = b0 + bs * 16 + lg * 4 + r;
                out[bb * NO + ob] = acc[bs][os][r];
            }
        }
}

extern "C" void kernel_launch(void* const* d_in, const int* in_sizes, int n_in,
                              void* d_out, int out_size, void* d_ws, size_t ws_size,
                              hipStream_t stream) {
    const float* x  = (const float*)d_in[0];
    const float* w0 = (const float*)d_in[1];
    const float* w1 = (const float*)d_in[2];
    const float* w2 = (const float*)d_in[3];
    const float* w3 = (const float*)d_in[4];
    const float* w4 = (const float*)d_in[5];
    float* out = (float*)d_out;

    ushort* Wh = (ushort*)d_ws;            // 232*512*8*2 = 1,900,544 B

    pinet_fold<<<NO, 1024, 0, stream>>>(w0, w1, w2, w3, w4, Wh);
    pinet_gemm<<<NB / 32, 1024, 0, stream>>>(x, Wh, out);
}

// Round 18
// 47.707 us; speedup vs baseline: 1.0865x; 1.0865x over previous
//
#include <hip/hip_runtime.h>
#include <hip/hip_bf16.h>
#include <cstdint>

// PiNet: B=8192, I=12, O=512, DEG=4.
// R17: R15 base with KT=128 (TPAD 1920 = 15*128): 15 sync windows instead of
// 29. B single-set loaded at window top (gen phase covers L2 latency); same
// 2-buffer Ash (16 KB), same swizzle scheme extended to 16 slots.

#define NB 8192
#define NI 12
#define NO 512
#define T_TOTAL 1820
#define TPAD 1920          // 15 * 128
#define NKT 15
#define B2 13
#define B3 91
#define B4 455

typedef __attribute__((ext_vector_type(8))) _Float16 f16x8;
typedef __attribute__((ext_vector_type(4))) float f32x4;

#define MFMA16(a, b, c) __builtin_amdgcn_mfma_f32_16x16x32_f16(a, b, c, 0, 0, 0)

__device__ __forceinline__ unsigned short f2h(float f) {
    _Float16 h = (_Float16)f;
    return __builtin_bit_cast(unsigned short, h);
}
__device__ __forceinline__ float h2f(unsigned short u) {
    return (float)__builtin_bit_cast(_Float16, u);
}

// ---------- compile-time tables ----------
constexpr int H2c(int n) { return n * (n + 1) / 2; }
constexpr int H3c(int n) { return n * (n + 1) * (n + 2) / 6; }
constexpr int rank2c(int a, int b) {
    int r = 0;
    for (int j = 0; j < a; ++j) r += NI - j;
    return r + (b - a);
}

struct alignas(16) MPArr { uint32_t v[TPAD]; };
constexpr MPArr gen_mp() {
    MPArr m{};
    for (int t = 0; t < TPAD; ++t) {
        uint32_t v = 0;
        if (t == 0) {
            v = 0;
        } else if (t < B2) {
            v = (uint32_t)t;
        } else if (t < B3) {
            int r = t - B2, a = 0;
            while (r >= NI - a) { r -= NI - a; ++a; }
            int b = a + r;
            v = (uint32_t)(1 + a) | ((uint32_t)(1 + b) << 16);
        } else if (t < B4) {
            int r = t - B3, a = 0;
            while (r >= H2c(NI - a)) { r -= H2c(NI - a); ++a; }
            int b = a;
            while (r >= NI - b) { r -= NI - b; ++b; }
            int c = b + r;
            v = (uint32_t)(13 + rank2c(a, b)) | ((uint32_t)(1 + c) << 16);
        } else if (t < T_TOTAL) {
            int r = t - B4, a = 0;
            while (r >= H3c(NI - a)) { r -= H3c(NI - a); ++a; }
            int b = a;
            while (r >= H2c(NI - b)) { r -= H2c(NI - b); ++b; }
            int c = b;
            while (r >= NI - c) { r -= NI - c; ++c; }
            int d = c + r;
            v = (uint32_t)(13 + rank2c(a, b)) | ((uint32_t)(13 + rank2c(c, d)) << 16);
        }
        m.v[t] = v;          // t in [1820,1920): monomial = 1, weight 0
    }
    return m;
}
__device__ constexpr MPArr MP = gen_mp();

struct FoldArr {
    uint16_t tup2[78];  float rk2[78];
    uint16_t tup3[364]; float rk3[364];
    uint16_t tup4[1368]; float rk4[1368];
};
constexpr FoldArr gen_fold() {
    FoldArr f{};
    for (int q = 0; q < 78; ++q) {
        int r = q, a = 0;
        while (r >= NI - a) { r -= NI - a; ++a; }
        int b = a + r;
        f.tup2[q] = (uint16_t)(a | (b << 4));
        f.rk2[q] = (a == b) ? 0.5f : 1.0f;
    }
    for (int q = 0; q < 364; ++q) {
        int r = q, a = 0;
        while (r >= H2c(NI - a)) { r -= H2c(NI - a); ++a; }
        int b = a;
        while (r >= NI - b) { r -= NI - b; ++b; }
        int c = b + r;
        f.tup3[q] = (uint16_t)(a | (b << 4) | (c << 8));
        int k = 1, run = 1;
        if (b == a) { ++run; k *= run; } else run = 1;
        if (c == b) { ++run; k *= run; } else run = 1;
        f.rk3[q] = 1.0f / (float)k;
    }
    for (int q = 0; q < 1365; ++q) {
        int r = q, a = 0;
        while (r >= H3c(NI - a)) { r -= H3c(NI - a); ++a; }
        int b = a;
        while (r >= H2c(NI - b)) { r -= H2c(NI - b); ++b; }
        int c = b;
        while (r >= NI - c) { r -= NI - c; ++c; }
        int d = c + r;
        f.tup4[q] = (uint16_t)(a | (b << 4) | (c << 8) | (d << 12));
        int k = 1, run = 1;
        if (b == a) { ++run; k *= run; } else run = 1;
        if (c == b) { ++run; k *= run; } else run = 1;
        if (d == c) { ++run; k *= run; } else run = 1;
        f.rk4[q] = 1.0f / (float)k;
    }
    return f;
}
__device__ constexpr FoldArr FT = gen_fold();

// ---------- fold: fp16 LDS staging (2 blocks/CU) + per-t orbit gather ----------
__global__ __launch_bounds__(1024, 8) void pinet_fold(
    const float* __restrict__ w0, const float* __restrict__ w1,
    const float* __restrict__ w2, const float* __restrict__ w3,
    const float* __restrict__ w4, ushort* __restrict__ Wh) {
    __shared__ ushort sw4h[20736];
    __shared__ ushort sw3h[1728];
    __shared__ ushort sw2h[144];
    const int tid = threadIdx.x;
    const int o = blockIdx.x;

    {   // coalesced staging, f32 -> fp16
        const float4* g4 = (const float4*)(w4 + o * 20736);
        for (int i = tid; i < 5184; i += 1024) {
            float4 v = g4[i];
            ushort4 h = {f2h(v.x), f2h(v.y), f2h(v.z), f2h(v.w)};
            *(ushort4*)&sw4h[i * 4] = h;
        }
        if (tid < 432) {
            float4 v = ((const float4*)(w3 + o * 1728))[tid];
            ushort4 h = {f2h(v.x), f2h(v.y), f2h(v.z), f2h(v.w)};
            *(ushort4*)&sw3h[tid * 4] = h;
        }
        if (tid < 36) {
            float4 v = ((const float4*)(w2 + o * 144))[tid];
            ushort4 h = {f2h(v.x), f2h(v.y), f2h(v.z), f2h(v.w)};
            *(ushort4*)&sw2h[tid * 4] = h;
        }
    }
    __syncthreads();

#define W4P(p, q, r, s_) h2f(sw4h[(p) * 1728 + (q) * 144 + (r) * 12 + (s_)])
#define W3P(p, q, r)     h2f(sw3h[(p) * 144 + (q) * 12 + (r)])
    for (int t = tid; t < TPAD; t += 1024) {
        float s = 0.0f;
        if (t == 0) {
            s = w0[o];
        } else if (t < B2) {
            s = w1[o * 12 + (t - 1)];
        } else if (t < B3) {
            int q = t - B2; int tp = FT.tup2[q];
            int a = tp & 15, b = (tp >> 4) & 15;
            s = (h2f(sw2h[a * 12 + b]) + h2f(sw2h[b * 12 + a])) * FT.rk2[q];
        } else if (t < B4) {
            int q = t - B3; int tp = FT.tup3[q];
            int a = tp & 15, b = (tp >> 4) & 15, c = (tp >> 8) & 15;
            s = (W3P(a, b, c) + W3P(a, c, b) + W3P(b, a, c) +
                 W3P(b, c, a) + W3P(c, a, b) + W3P(c, b, a)) * FT.rk3[q];
        } else if (t < T_TOTAL) {
            int q = t - B4; int tp = FT.tup4[q];
            int a = tp & 15, b = (tp >> 4) & 15, c = (tp >> 8) & 15, d = (tp >> 12) & 15;
            float s4v =
                W4P(a,b,c,d) + W4P(a,b,d,c) + W4P(a,c,b,d) + W4P(a,c,d,b) +
                W4P(a,d,b,c) + W4P(a,d,c,b) + W4P(b,a,c,d) + W4P(b,a,d,c) +
                W4P(b,c,a,d) + W4P(b,c,d,a) + W4P(b,d,a,c) + W4P(b,d,c,a) +
                W4P(c,a,b,d) + W4P(c,a,d,b) + W4P(c,b,a,d) + W4P(c,b,d,a) +
                W4P(c,d,a,b) + W4P(c,d,b,a) + W4P(d,a,b,c) + W4P(d,a,c,b) +
                W4P(d,b,a,c) + W4P(d,b,c,a) + W4P(d,c,a,b) + W4P(d,c,b,a);
            s = s4v * FT.rk4[q];
        }
        Wh[((t >> 3) * NO + o) * 8 + (t & 7)] = f2h(s);
    }
#undef W4P
#undef W3P
}

// ---------- MFMA GEMM: out[b,o] = sum_t M[t][b] * Wt[t][o], fp16 ----------
// Block: 32 b x 512 o, 1024 threads (16 waves of 32b x 32o), grid 256 = 1/CU.
// KT=128: 15 windows, 1 __syncthreads each. B single-set loaded at window top.
__global__ __launch_bounds__(1024, 4) void pinet_gemm(
    const float* __restrict__ x, const ushort* __restrict__ Wh,
    float* __restrict__ out) {
    __shared__ float msm[32][93];           // per-b: {1, x0..x11, 78 deg2}
    __shared__ ushort Ash[2][32][16][8];    // [buf][b][t-octet slot (swz 16)][8]

    const int tid = threadIdx.x;
    const int b0 = blockIdx.x * 32;

    for (int idx = tid; idx < 32 * 13; idx += 1024) {
        int b = idx / 13, j = idx % 13;
        msm[b][j] = (j == 0) ? 1.0f : x[(b0 + b) * 12 + (j - 1)];
    }
    __syncthreads();
    for (int idx = tid; idx < 32 * 78; idx += 1024) {
        int b = idx / 78, q = idx % 78;
        uint32_t m2 = MP.v[B2 + q];
        msm[b][13 + q] = msm[b][m2 & 0xFFFFu] * msm[b][m2 >> 16];
    }

    const int l = tid & 63, wv = tid >> 6;  // 16 waves, wO = wv (512 o total)
    const int lm = l & 15, lg = l >> 4;
    const int o_w = wv * 32;
    const int bgen = tid & 31;
    const int task = tid >> 5;              // 0..31, 4 t's each (128 t / kt)
    const int sA = (task >> 1) ^ (bgen & 15);
    const int hOf = (task & 1) * 4;

    f32x4 acc[2][2] = {};
    f16x8 Bv[4][2];                         // [c][os], single set

    auto gen = [&](int kt, int buf) {
        int t0 = kt * 128 + task * 4;
        uint4 mq = *(const uint4*)&MP.v[t0];
        const float* row = msm[bgen];
        uint32_t mqs[4] = {mq.x, mq.y, mq.z, mq.w};
        unsigned short vv[4];
#pragma unroll
        for (int j = 0; j < 4; ++j) {
            float p = row[mqs[j] & 0xFFFFu] * row[mqs[j] >> 16];
            vv[j] = f2h(p);
        }
        ushort4 v = {vv[0], vv[1], vv[2], vv[3]};
        *(ushort4*)&Ash[buf][bgen][sA][hOf] = v;
    };
    auto loadB = [&](int kt) {
#pragma unroll
        for (int c = 0; c < 4; ++c)
#pragma unroll
            for (int os = 0; os < 2; ++os) {
                int pk = kt * 16 + c * 4 + lg;
                Bv[c][os] = *(const f16x8*)(Wh + (pk * NO + o_w + os * 16 + lm) * 8);
            }
    };
    auto mfmaR = [&](int cur) {
#pragma unroll
        for (int c = 0; c < 4; ++c) {
            f16x8 a[2];
#pragma unroll
            for (int bs = 0; bs < 2; ++bs) {
                int br = bs * 16 + lm;
                a[bs] = *(const f16x8*)&Ash[cur][br][(c * 4 + lg) ^ (br & 15)][0];
            }
#pragma unroll
            for (int bs = 0; bs < 2; ++bs)
#pragma unroll
                for (int os = 0; os < 2; ++os)
                    acc[bs][os] = MFMA16(a[bs], Bv[c][os], acc[bs][os]);
        }
    };

    __syncthreads();          // msm ready
    gen(0, 0);
    __syncthreads();          // Ash[0] ready

    for (int kt = 0; kt < NKT; ++kt) {
        const int buf = kt & 1;
        loadB(kt);                        // issued up front; gen covers latency
        if (kt + 1 < NKT) gen(kt + 1, buf ^ 1);
        mfmaR(buf);
        __syncthreads();
    }

#pragma unroll
    for (int bs = 0; bs < 2; ++bs)
#pragma unroll
        for (int os = 0; os < 2; ++os) {
            int ob = o_w + os * 16 + lm;
#pragma unroll
            for (int r = 0; r < 4; ++r) {
                int bb = b0 + bs * 16 + lg * 4 + r;
                out[bb * NO + ob] = acc[bs][os][r];
            }
        }
}

extern "C" void kernel_launch(void* const* d_in, const int* in_sizes, int n_in,
                              void* d_out, int out_size, void* d_ws, size_t ws_size,
                              hipStream_t stream) {
    const float* x  = (const float*)d_in[0];
    const float* w0 = (const float*)d_in[1];
    const float* w1 = (const float*)d_in[2];
    const float* w2 = (const float*)d_in[3];
    const float* w3 = (const float*)d_in[4];
    const float* w4 = (const float*)d_in[5];
    float* out = (float*)d_out;

    ushort* Wh = (ushort*)d_ws;            // 240*512*8*2 = 1,966,080 B

    pinet_fold<<<NO, 1024, 0, stream>>>(w0, w1, w2, w3, w4, Wh);
    pinet_gemm<<<NB / 32, 1024, 0, stream>>>(x, Wh, out);
}

// Round 19
// 44.053 us; speedup vs baseline: 1.1767x; 1.0829x over previous
//
#include <hip/hip_runtime.h>
#include <hip/hip_bf16.h>
#include <cstdint>

// PiNet: B=8192, I=12, O=512, DEG=4.
// R18: R17 base + K-SPLIT gemm: 16 waves = 2 k-groups x 8 o-groups, wave
// 32b x 64o x K/2. A-frag LDS reads halve (each wave reads only its K-half);
// B volume unchanged (kg disjoint in k, og in o). One-time cross-kg reduce
// through a 64KB LDS overlay (msm/Ash dead by then). Fold unchanged.

#define NB 8192
#define NI 12
#define NO 512
#define T_TOTAL 1820
#define TPAD 1920          // 15 * 128
#define NKT 15
#define B2 13
#define B3 91
#define B4 455

typedef __attribute__((ext_vector_type(8))) _Float16 f16x8;
typedef __attribute__((ext_vector_type(4))) float f32x4;

#define MFMA16(a, b, c) __builtin_amdgcn_mfma_f32_16x16x32_f16(a, b, c, 0, 0, 0)

__device__ __forceinline__ unsigned short f2h(float f) {
    _Float16 h = (_Float16)f;
    return __builtin_bit_cast(unsigned short, h);
}
__device__ __forceinline__ float h2f(unsigned short u) {
    return (float)__builtin_bit_cast(_Float16, u);
}

// ---------- compile-time tables ----------
constexpr int H2c(int n) { return n * (n + 1) / 2; }
constexpr int H3c(int n) { return n * (n + 1) * (n + 2) / 6; }
constexpr int rank2c(int a, int b) {
    int r = 0;
    for (int j = 0; j < a; ++j) r += NI - j;
    return r + (b - a);
}

struct alignas(16) MPArr { uint32_t v[TPAD]; };
constexpr MPArr gen_mp() {
    MPArr m{};
    for (int t = 0; t < TPAD; ++t) {
        uint32_t v = 0;
        if (t == 0) {
            v = 0;
        } else if (t < B2) {
            v = (uint32_t)t;
        } else if (t < B3) {
            int r = t - B2, a = 0;
            while (r >= NI - a) { r -= NI - a; ++a; }
            int b = a + r;
            v = (uint32_t)(1 + a) | ((uint32_t)(1 + b) << 16);
        } else if (t < B4) {
            int r = t - B3, a = 0;
            while (r >= H2c(NI - a)) { r -= H2c(NI - a); ++a; }
            int b = a;
            while (r >= NI - b) { r -= NI - b; ++b; }
            int c = b + r;
            v = (uint32_t)(13 + rank2c(a, b)) | ((uint32_t)(1 + c) << 16);
        } else if (t < T_TOTAL) {
            int r = t - B4, a = 0;
            while (r >= H3c(NI - a)) { r -= H3c(NI - a); ++a; }
            int b = a;
            while (r >= H2c(NI - b)) { r -= H2c(NI - b); ++b; }
            int c = b;
            while (r >= NI - c) { r -= NI - c; ++c; }
            int d = c + r;
            v = (uint32_t)(13 + rank2c(a, b)) | ((uint32_t)(13 + rank2c(c, d)) << 16);
        }
        m.v[t] = v;          // t in [1820,1920): monomial = 1, weight 0
    }
    return m;
}
__device__ constexpr MPArr MP = gen_mp();

struct FoldArr {
    uint16_t tup2[78];  float rk2[78];
    uint16_t tup3[364]; float rk3[364];
    uint16_t tup4[1368]; float rk4[1368];
};
constexpr FoldArr gen_fold() {
    FoldArr f{};
    for (int q = 0; q < 78; ++q) {
        int r = q, a = 0;
        while (r >= NI - a) { r -= NI - a; ++a; }
        int b = a + r;
        f.tup2[q] = (uint16_t)(a | (b << 4));
        f.rk2[q] = (a == b) ? 0.5f : 1.0f;
    }
    for (int q = 0; q < 364; ++q) {
        int r = q, a = 0;
        while (r >= H2c(NI - a)) { r -= H2c(NI - a); ++a; }
        int b = a;
        while (r >= NI - b) { r -= NI - b; ++b; }
        int c = b + r;
        f.tup3[q] = (uint16_t)(a | (b << 4) | (c << 8));
        int k = 1, run = 1;
        if (b == a) { ++run; k *= run; } else run = 1;
        if (c == b) { ++run; k *= run; } else run = 1;
        f.rk3[q] = 1.0f / (float)k;
    }
    for (int q = 0; q < 1365; ++q) {
        int r = q, a = 0;
        while (r >= H3c(NI - a)) { r -= H3c(NI - a); ++a; }
        int b = a;
        while (r >= H2c(NI - b)) { r -= H2c(NI - b); ++b; }
        int c = b;
        while (r >= NI - c) { r -= NI - c; ++c; }
        int d = c + r;
        f.tup4[q] = (uint16_t)(a | (b << 4) | (c << 8) | (d << 12));
        int k = 1, run = 1;
        if (b == a) { ++run; k *= run; } else run = 1;
        if (c == b) { ++run; k *= run; } else run = 1;
        if (d == c) { ++run; k *= run; } else run = 1;
        f.rk4[q] = 1.0f / (float)k;
    }
    return f;
}
__device__ constexpr FoldArr FT = gen_fold();

// ---------- fold: fp16 LDS staging (2 blocks/CU) + per-t orbit gather ----------
__global__ __launch_bounds__(1024, 8) void pinet_fold(
    const float* __restrict__ w0, const float* __restrict__ w1,
    const float* __restrict__ w2, const float* __restrict__ w3,
    const float* __restrict__ w4, ushort* __restrict__ Wh) {
    __shared__ ushort sw4h[20736];
    __shared__ ushort sw3h[1728];
    __shared__ ushort sw2h[144];
    const int tid = threadIdx.x;
    const int o = blockIdx.x;

    {   // coalesced staging, f32 -> fp16
        const float4* g4 = (const float4*)(w4 + o * 20736);
        for (int i = tid; i < 5184; i += 1024) {
            float4 v = g4[i];
            ushort4 h = {f2h(v.x), f2h(v.y), f2h(v.z), f2h(v.w)};
            *(ushort4*)&sw4h[i * 4] = h;
        }
        if (tid < 432) {
            float4 v = ((const float4*)(w3 + o * 1728))[tid];
            ushort4 h = {f2h(v.x), f2h(v.y), f2h(v.z), f2h(v.w)};
            *(ushort4*)&sw3h[tid * 4] = h;
        }
        if (tid < 36) {
            float4 v = ((const float4*)(w2 + o * 144))[tid];
            ushort4 h = {f2h(v.x), f2h(v.y), f2h(v.z), f2h(v.w)};
            *(ushort4*)&sw2h[tid * 4] = h;
        }
    }
    __syncthreads();

#define W4P(p, q, r, s_) h2f(sw4h[(p) * 1728 + (q) * 144 + (r) * 12 + (s_)])
#define W3P(p, q, r)     h2f(sw3h[(p) * 144 + (q) * 12 + (r)])
    for (int t = tid; t < TPAD; t += 1024) {
        float s = 0.0f;
        if (t == 0) {
            s = w0[o];
        } else if (t < B2) {
            s = w1[o * 12 + (t - 1)];
        } else if (t < B3) {
            int q = t - B2; int tp = FT.tup2[q];
            int a = tp & 15, b = (tp >> 4) & 15;
            s = (h2f(sw2h[a * 12 + b]) + h2f(sw2h[b * 12 + a])) * FT.rk2[q];
        } else if (t < B4) {
            int q = t - B3; int tp = FT.tup3[q];
            int a = tp & 15, b = (tp >> 4) & 15, c = (tp >> 8) & 15;
            s = (W3P(a, b, c) + W3P(a, c, b) + W3P(b, a, c) +
                 W3P(b, c, a) + W3P(c, a, b) + W3P(c, b, a)) * FT.rk3[q];
        } else if (t < T_TOTAL) {
            int q = t - B4; int tp = FT.tup4[q];
            int a = tp & 15, b = (tp >> 4) & 15, c = (tp >> 8) & 15, d = (tp >> 12) & 15;
            float s4v =
                W4P(a,b,c,d) + W4P(a,b,d,c) + W4P(a,c,b,d) + W4P(a,c,d,b) +
                W4P(a,d,b,c) + W4P(a,d,c,b) + W4P(b,a,c,d) + W4P(b,a,d,c) +
                W4P(b,c,a,d) + W4P(b,c,d,a) + W4P(b,d,a,c) + W4P(b,d,c,a) +
                W4P(c,a,b,d) + W4P(c,a,d,b) + W4P(c,b,a,d) + W4P(c,b,d,a) +
                W4P(c,d,a,b) + W4P(c,d,b,a) + W4P(d,a,b,c) + W4P(d,a,c,b) +
                W4P(d,b,a,c) + W4P(d,b,c,a) + W4P(d,c,a,b) + W4P(d,c,b,a);
            s = s4v * FT.rk4[q];
        }
        Wh[((t >> 3) * NO + o) * 8 + (t & 7)] = f2h(s);
    }
#undef W4P
#undef W3P
}

// ---------- MFMA GEMM: out[b,o] = sum_t M[t][b] * Wt[t][o], fp16 ----------
// Block: 32 b x 512 o, 1024 threads = 2 k-groups x 8 o-groups, wave
// 32b x 64o x K/2. Grid 256 = 1/CU. KT=128, 15 windows. Cross-kg reduce
// via 64KB LDS overlay at the end.
__global__ __launch_bounds__(1024, 4) void pinet_gemm(
    const float* __restrict__ x, const ushort* __restrict__ Wh,
    float* __restrict__ out) {
    __shared__ __align__(16) uint8_t smem[65536];
    float (*msm)[93] = (float(*)[93])smem;                 // 32*93*4 = 11904 B
    typedef ushort AshT[2][32][16][8];
    AshT& ash = *(AshT*)(smem + 11904);                    // 16384 B -> 28288
    float* red = (float*)smem;                             // 64KB overlay (post-loop)

    const int tid = threadIdx.x;
    const int b0 = blockIdx.x * 32;

    for (int idx = tid; idx < 32 * 13; idx += 1024) {
        int b = idx / 13, j = idx % 13;
        msm[b][j] = (j == 0) ? 1.0f : x[(b0 + b) * 12 + (j - 1)];
    }
    __syncthreads();
    for (int idx = tid; idx < 32 * 78; idx += 1024) {
        int b = idx / 78, q = idx % 78;
        uint32_t m2 = MP.v[B2 + q];
        msm[b][13 + q] = msm[b][m2 & 0xFFFFu] * msm[b][m2 >> 16];
    }

    const int l = tid & 63, wv = tid >> 6;  // 16 waves
    const int lm = l & 15, lg = l >> 4;
    const int kg = wv >> 3, og = wv & 7;    // 2 k-groups x 8 o-groups
    const int o_w = og * 64;
    const int bgen = tid & 31;
    const int task = tid >> 5;              // 0..31, 4 t's each (128 t / kt)
    const int sA = (task >> 1) ^ (bgen & 15);
    const int hOf = (task & 1) * 4;

    f32x4 acc[2][4] = {};                   // [bs][os]
    f16x8 Bv[2][4];                         // [c][os], own K-half only

    auto gen = [&](int kt, int buf) {
        int t0 = kt * 128 + task * 4;
        uint4 mq = *(const uint4*)&MP.v[t0];
        const float* row = msm[bgen];
        uint32_t mqs[4] = {mq.x, mq.y, mq.z, mq.w};
        unsigned short vv[4];
#pragma unroll
        for (int j = 0; j < 4; ++j) {
            float p = row[mqs[j] & 0xFFFFu] * row[mqs[j] >> 16];
            vv[j] = f2h(p);
        }
        ushort4 v = {vv[0], vv[1], vv[2], vv[3]};
        *(ushort4*)&ash[buf][bgen][sA][hOf] = v;
    };
    auto loadB = [&](int kt) {
#pragma unroll
        for (int c = 0; c < 2; ++c)
#pragma unroll
            for (int os = 0; os < 4; ++os) {
                int pk = kt * 16 + kg * 8 + c * 4 + lg;
                Bv[c][os] = *(const f16x8*)(Wh + (pk * NO + o_w + os * 16 + lm) * 8);
            }
    };
    auto mfmaR = [&](int cur) {
#pragma unroll
        for (int c = 0; c < 2; ++c) {
            f16x8 a[2];
#pragma unroll
            for (int bs = 0; bs < 2; ++bs) {
                int br = bs * 16 + lm;
                int oct = kg * 8 + c * 4 + lg;
                a[bs] = *(const f16x8*)&ash[cur][br][oct ^ (br & 15)][0];
            }
#pragma unroll
            for (int bs = 0; bs < 2; ++bs)
#pragma unroll
                for (int os = 0; os < 4; ++os)
                    acc[bs][os] = MFMA16(a[bs], Bv[c][os], acc[bs][os]);
        }
    };

    __syncthreads();          // msm ready
    gen(0, 0);
    __syncthreads();          // ash[0] ready

    for (int kt = 0; kt < NKT; ++kt) {
        const int buf = kt & 1;
        loadB(kt);                        // own K-half; gen covers latency
        if (kt + 1 < NKT) gen(kt + 1, buf ^ 1);
        mfmaR(buf);
        __syncthreads();
    }
    // after final barrier: all msm/ash reads complete -> red overlay is safe

    if (kg == 1) {
#pragma unroll
        for (int bs = 0; bs < 2; ++bs)
#pragma unroll
            for (int os = 0; os < 4; ++os)
                *(f32x4*)&red[(((og * 2 + bs) * 4 + os) * 64 + l) * 4] = acc[bs][os];
    }
    __syncthreads();
    if (kg == 0) {
#pragma unroll
        for (int bs = 0; bs < 2; ++bs)
#pragma unroll
            for (int os = 0; os < 4; ++os) {
                f32x4 v = *(const f32x4*)&red[(((og * 2 + bs) * 4 + os) * 64 + l) * 4];
                acc[bs][os] += v;
                int ob = o_w + os * 16 + lm;
#pragma unroll
                for (int r = 0; r < 4; ++r) {
                    int bb = b0 + bs * 16 + lg * 4 + r;
                    out[bb * NO + ob] = acc[bs][os][r];
                }
            }
    }
}

extern "C" void kernel_launch(void* const* d_in, const int* in_sizes, int n_in,
                              void* d_out, int out_size, void* d_ws, size_t ws_size,
                              hipStream_t stream) {
    const float* x  = (const float*)d_in[0];
    const float* w0 = (const float*)d_in[1];
    const float* w1 = (const float*)d_in[2];
    const float* w2 = (const float*)d_in[3];
    const float* w3 = (const float*)d_in[4];
    const float* w4 = (const float*)d_in[5];
    float* out = (float*)d_out;

    ushort* Wh = (ushort*)d_ws;            // 240*512*8*2 = 1,966,080 B

    pinet_fold<<<NO, 1024, 0, stream>>>(w0, w1, w2, w3, w4, Wh);
    pinet_gemm<<<NB / 32, 1024, 0, stream>>>(x, Wh, out);
}

// Round 20
// 42.453 us; speedup vs baseline: 1.2210x; 1.0377x over previous
//
#include <hip/hip_runtime.h>
#include <hip/hip_bf16.h>
#include <cstdint>

// PiNet: B=8192, I=12, O=512, DEG=4.
// R19: R18 base; fold's staged weight layout padded to conflict-free LDS
// strides (u16 strides 1780/148/12/1 -> dword steps 26/10/6, >=16 banks on
// every permutation term; old 1728/144 gave 1- and 4-bank 12-way conflicts).
// Gemm (K-split, KT=128) byte-identical to R18.

#define NB 8192
#define NI 12
#define NO 512
#define T_TOTAL 1820
#define TPAD 1920          // 15 * 128
#define NKT 15
#define B2 13
#define B3 91
#define B4 455

// padded LDS strides for staged w4/w3 (u16 units)
#define P4S 1780
#define Q4S 148
#define P3S 148

typedef __attribute__((ext_vector_type(8))) _Float16 f16x8;
typedef __attribute__((ext_vector_type(4))) float f32x4;

#define MFMA16(a, b, c) __builtin_amdgcn_mfma_f32_16x16x32_f16(a, b, c, 0, 0, 0)

__device__ __forceinline__ unsigned short f2h(float f) {
    _Float16 h = (_Float16)f;
    return __builtin_bit_cast(unsigned short, h);
}
__device__ __forceinline__ float h2f(unsigned short u) {
    return (float)__builtin_bit_cast(_Float16, u);
}

// ---------- compile-time tables ----------
constexpr int H2c(int n) { return n * (n + 1) / 2; }
constexpr int H3c(int n) { return n * (n + 1) * (n + 2) / 6; }
constexpr int rank2c(int a, int b) {
    int r = 0;
    for (int j = 0; j < a; ++j) r += NI - j;
    return r + (b - a);
}

struct alignas(16) MPArr { uint32_t v[TPAD]; };
constexpr MPArr gen_mp() {
    MPArr m{};
    for (int t = 0; t < TPAD; ++t) {
        uint32_t v = 0;
        if (t == 0) {
            v = 0;
        } else if (t < B2) {
            v = (uint32_t)t;
        } else if (t < B3) {
            int r = t - B2, a = 0;
            while (r >= NI - a) { r -= NI - a; ++a; }
            int b = a + r;
            v = (uint32_t)(1 + a) | ((uint32_t)(1 + b) << 16);
        } else if (t < B4) {
            int r = t - B3, a = 0;
            while (r >= H2c(NI - a)) { r -= H2c(NI - a); ++a; }
            int b = a;
            while (r >= NI - b) { r -= NI - b; ++b; }
            int c = b + r;
            v = (uint32_t)(13 + rank2c(a, b)) | ((uint32_t)(1 + c) << 16);
        } else if (t < T_TOTAL) {
            int r = t - B4, a = 0;
            while (r >= H3c(NI - a)) { r -= H3c(NI - a); ++a; }
            int b = a;
            while (r >= H2c(NI - b)) { r -= H2c(NI - b); ++b; }
            int c = b;
            while (r >= NI - c) { r -= NI - c; ++c; }
            int d = c + r;
            v = (uint32_t)(13 + rank2c(a, b)) | ((uint32_t)(13 + rank2c(c, d)) << 16);
        }
        m.v[t] = v;          // t in [1820,1920): monomial = 1, weight 0
    }
    return m;
}
__device__ constexpr MPArr MP = gen_mp();

struct FoldArr {
    uint16_t tup2[78];  float rk2[78];
    uint16_t tup3[364]; float rk3[364];
    uint16_t tup4[1368]; float rk4[1368];
};
constexpr FoldArr gen_fold() {
    FoldArr f{};
    for (int q = 0; q < 78; ++q) {
        int r = q, a = 0;
        while (r >= NI - a) { r -= NI - a; ++a; }
        int b = a + r;
        f.tup2[q] = (uint16_t)(a | (b << 4));
        f.rk2[q] = (a == b) ? 0.5f : 1.0f;
    }
    for (int q = 0; q < 364; ++q) {
        int r = q, a = 0;
        while (r >= H2c(NI - a)) { r -= H2c(NI - a); ++a; }
        int b = a;
        while (r >= NI - b) { r -= NI - b; ++b; }
        int c = b + r;
        f.tup3[q] = (uint16_t)(a | (b << 4) | (c << 8));
        int k = 1, run = 1;
        if (b == a) { ++run; k *= run; } else run = 1;
        if (c == b) { ++run; k *= run; } else run = 1;
        f.rk3[q] = 1.0f / (float)k;
    }
    for (int q = 0; q < 1365; ++q) {
        int r = q, a = 0;
        while (r >= H3c(NI - a)) { r -= H3c(NI - a); ++a; }
        int b = a;
        while (r >= H2c(NI - b)) { r -= H2c(NI - b); ++b; }
        int c = b;
        while (r >= NI - c) { r -= NI - c; ++c; }
        int d = c + r;
        f.tup4[q] = (uint16_t)(a | (b << 4) | (c << 8) | (d << 12));
        int k = 1, run = 1;
        if (b == a) { ++run; k *= run; } else run = 1;
        if (c == b) { ++run; k *= run; } else run = 1;
        if (d == c) { ++run; k *= run; } else run = 1;
        f.rk4[q] = 1.0f / (float)k;
    }
    return f;
}
__device__ constexpr FoldArr FT = gen_fold();

// ---------- fold: fp16 LDS staging (padded strides) + per-t orbit gather ------
__global__ __launch_bounds__(1024, 8) void pinet_fold(
    const float* __restrict__ w0, const float* __restrict__ w1,
    const float* __restrict__ w2, const float* __restrict__ w3,
    const float* __restrict__ w4, ushort* __restrict__ Wh) {
    __shared__ ushort sw4h[12 * P4S];   // 21360 u16, strides (1780,148,12,1)
    __shared__ ushort sw3h[12 * P3S];   // 1776 u16,  strides (148,12,1)
    __shared__ ushort sw2h[144];
    const int tid = threadIdx.x;
    const int o = blockIdx.x;

    {   // coalesced staging, f32 -> fp16, remapped to padded layout
        const float4* g4 = (const float4*)(w4 + o * 20736);
        for (int i = tid; i < 5184; i += 1024) {
            float4 v = g4[i];
            int c0 = i * 4;
            int p = c0 / 1728, rem = c0 % 1728;
            int q = rem / 144, r2 = rem % 144;
            int r = r2 / 12, s0 = r2 % 12;
            ushort4 h = {f2h(v.x), f2h(v.y), f2h(v.z), f2h(v.w)};
            *(ushort4*)&sw4h[p * P4S + q * Q4S + r * 12 + s0] = h;
        }
        if (tid < 432) {
            float4 v = ((const float4*)(w3 + o * 1728))[tid];
            int c0 = tid * 4;
            int a = c0 / 144, rem = c0 % 144;
            int b = rem / 12, s0 = rem % 12;
            ushort4 h = {f2h(v.x), f2h(v.y), f2h(v.z), f2h(v.w)};
            *(ushort4*)&sw3h[a * P3S + b * 12 + s0] = h;
        }
        if (tid < 36) {
            float4 v = ((const float4*)(w2 + o * 144))[tid];
            ushort4 h = {f2h(v.x), f2h(v.y), f2h(v.z), f2h(v.w)};
            *(ushort4*)&sw2h[tid * 4] = h;
        }
    }
    __syncthreads();

#define W4P(p, q, r, s_) h2f(sw4h[(p) * P4S + (q) * Q4S + (r) * 12 + (s_)])
#define W3P(p, q, r)     h2f(sw3h[(p) * P3S + (q) * 12 + (r)])
    for (int t = tid; t < TPAD; t += 1024) {
        float s = 0.0f;
        if (t == 0) {
            s = w0[o];
        } else if (t < B2) {
            s = w1[o * 12 + (t - 1)];
        } else if (t < B3) {
            int q = t - B2; int tp = FT.tup2[q];
            int a = tp & 15, b = (tp >> 4) & 15;
            s = (h2f(sw2h[a * 12 + b]) + h2f(sw2h[b * 12 + a])) * FT.rk2[q];
        } else if (t < B4) {
            int q = t - B3; int tp = FT.tup3[q];
            int a = tp & 15, b = (tp >> 4) & 15, c = (tp >> 8) & 15;
            s = (W3P(a, b, c) + W3P(a, c, b) + W3P(b, a, c) +
                 W3P(b, c, a) + W3P(c, a, b) + W3P(c, b, a)) * FT.rk3[q];
        } else if (t < T_TOTAL) {
            int q = t - B4; int tp = FT.tup4[q];
            int a = tp & 15, b = (tp >> 4) & 15, c = (tp >> 8) & 15, d = (tp >> 12) & 15;
            float s4v =
                W4P(a,b,c,d) + W4P(a,b,d,c) + W4P(a,c,b,d) + W4P(a,c,d,b) +
                W4P(a,d,b,c) + W4P(a,d,c,b) + W4P(b,a,c,d) + W4P(b,a,d,c) +
                W4P(b,c,a,d) + W4P(b,c,d,a) + W4P(b,d,a,c) + W4P(b,d,c,a) +
                W4P(c,a,b,d) + W4P(c,a,d,b) + W4P(c,b,a,d) + W4P(c,b,d,a) +
                W4P(c,d,a,b) + W4P(c,d,b,a) + W4P(d,a,b,c) + W4P(d,a,c,b) +
                W4P(d,b,a,c) + W4P(d,b,c,a) + W4P(d,c,a,b) + W4P(d,c,b,a);
            s = s4v * FT.rk4[q];
        }
        Wh[((t >> 3) * NO + o) * 8 + (t & 7)] = f2h(s);
    }
#undef W4P
#undef W3P
}

// ---------- MFMA GEMM: identical to R18 (K-split, KT=128) ----------
__global__ __launch_bounds__(1024, 4) void pinet_gemm(
    const float* __restrict__ x, const ushort* __restrict__ Wh,
    float* __restrict__ out) {
    __shared__ __align__(16) uint8_t smem[65536];
    float (*msm)[93] = (float(*)[93])smem;                 // 32*93*4 = 11904 B
    typedef ushort AshT[2][32][16][8];
    AshT& ash = *(AshT*)(smem + 11904);                    // 16384 B -> 28288
    float* red = (float*)smem;                             // 64KB overlay (post-loop)

    const int tid = threadIdx.x;
    const int b0 = blockIdx.x * 32;

    for (int idx = tid; idx < 32 * 13; idx += 1024) {
        int b = idx / 13, j = idx % 13;
        msm[b][j] = (j == 0) ? 1.0f : x[(b0 + b) * 12 + (j - 1)];
    }
    __syncthreads();
    for (int idx = tid; idx < 32 * 78; idx += 1024) {
        int b = idx / 78, q = idx % 78;
        uint32_t m2 = MP.v[B2 + q];
        msm[b][13 + q] = msm[b][m2 & 0xFFFFu] * msm[b][m2 >> 16];
    }

    const int l = tid & 63, wv = tid >> 6;  // 16 waves
    const int lm = l & 15, lg = l >> 4;
    const int kg = wv >> 3, og = wv & 7;    // 2 k-groups x 8 o-groups
    const int o_w = og * 64;
    const int bgen = tid & 31;
    const int task = tid >> 5;              // 0..31, 4 t's each (128 t / kt)
    const int sA = (task >> 1) ^ (bgen & 15);
    const int hOf = (task & 1) * 4;

    f32x4 acc[2][4] = {};                   // [bs][os]
    f16x8 Bv[2][4];                         // [c][os], own K-half only

    auto gen = [&](int kt, int buf) {
        int t0 = kt * 128 + task * 4;
        uint4 mq = *(const uint4*)&MP.v[t0];
        const float* row = msm[bgen];
        uint32_t mqs[4] = {mq.x, mq.y, mq.z, mq.w};
        unsigned short vv[4];
#pragma unroll
        for (int j = 0; j < 4; ++j) {
            float p = row[mqs[j] & 0xFFFFu] * row[mqs[j] >> 16];
            vv[j] = f2h(p);
        }
        ushort4 v = {vv[0], vv[1], vv[2], vv[3]};
        *(ushort4*)&ash[buf][bgen][sA][hOf] = v;
    };
    auto loadB = [&](int kt) {
#pragma unroll
        for (int c = 0; c < 2; ++c)
#pragma unroll
            for (int os = 0; os < 4; ++os) {
                int pk = kt * 16 + kg * 8 + c * 4 + lg;
                Bv[c][os] = *(const f16x8*)(Wh + (pk * NO + o_w + os * 16 + lm) * 8);
            }
    };
    auto mfmaR = [&](int cur) {
#pragma unroll
        for (int c = 0; c < 2; ++c) {
            f16x8 a[2];
#pragma unroll
            for (int bs = 0; bs < 2; ++bs) {
                int br = bs * 16 + lm;
                int oct = kg * 8 + c * 4 + lg;
                a[bs] = *(const f16x8*)&ash[cur][br][oct ^ (br & 15)][0];
            }
#pragma unroll
            for (int bs = 0; bs < 2; ++bs)
#pragma unroll
                for (int os = 0; os < 4; ++os)
                    acc[bs][os] = MFMA16(a[bs], Bv[c][os], acc[bs][os]);
        }
    };

    __syncthreads();          // msm ready
    gen(0, 0);
    __syncthreads();          // ash[0] ready

    for (int kt = 0; kt < NKT; ++kt) {
        const int buf = kt & 1;
        loadB(kt);                        // own K-half; gen covers latency
        if (kt + 1 < NKT) gen(kt + 1, buf ^ 1);
        mfmaR(buf);
        __syncthreads();
    }
    // after final barrier: all msm/ash reads complete -> red overlay is safe

    if (kg == 1) {
#pragma unroll
        for (int bs = 0; bs < 2; ++bs)
#pragma unroll
            for (int os = 0; os < 4; ++os)
                *(f32x4*)&red[(((og * 2 + bs) * 4 + os) * 64 + l) * 4] = acc[bs][os];
    }
    __syncthreads();
    if (kg == 0) {
#pragma unroll
        for (int bs = 0; bs < 2; ++bs)
#pragma unroll
            for (int os = 0; os < 4; ++os) {
                f32x4 v = *(const f32x4*)&red[(((og * 2 + bs) * 4 + os) * 64 + l) * 4];
                acc[bs][os] += v;
                int ob = o_w + os * 16 + lm;
#pragma unroll
                for (int r = 0; r < 4; ++r) {
                    int bb = b0 + bs * 16 + lg * 4 + r;
                    out[bb * NO + ob] = acc[bs][os][r];
                }
            }
    }
}

extern "C" void kernel_launch(void* const* d_in, const int* in_sizes, int n_in,
                              void* d_out, int out_size, void* d_ws, size_t ws_size,
                              hipStream_t stream) {
    const float* x  = (const float*)d_in[0];
    const float* w0 = (const float*)d_in[1];
    const float* w1 = (const float*)d_in[2];
    const float* w2 = (const float*)d_in[3];
    const float* w3 = (const float*)d_in[4];
    const float* w4 = (const float*)d_in[5];
    float* out = (float*)d_out;

    ushort* Wh = (ushort*)d_ws;            // 240*512*8*2 = 1,966,080 B

    pinet_fold<<<NO, 1024, 0, stream>>>(w0, w1, w2, w3, w4, Wh);
    pinet_gemm<<<NB / 32, 1024, 0, stream>>>(x, Wh, out);
}